// Round 1
// baseline (484.646 us; speedup 1.0000x reference)
//
#include <hip/hip_runtime.h>
#include <stdint.h>

typedef __attribute__((ext_vector_type(8))) short bf16x8;
typedef __attribute__((ext_vector_type(4))) float f32x4;

#define NROWS 131072
#define HID   512
#define LAT   128
#define NCOL  768
#define BM    64

static __device__ __forceinline__ short f2bf(float f) {
    union { float f; uint32_t u; } v; v.f = f;
    uint32_t r = v.u + 0x7FFFu + ((v.u >> 16) & 1u);
    return (short)(r >> 16);
}

// ---------------------------------------------------------------------------
// prep: weights -> fragment-ready bf16 (B operand of mfma_f32_16x16x32_bf16),
// biases -> fp32[768], and zero the output accumulator.
// Layout: chunk index ((n*16 + ks)*64 + l), 16B per lane l:
//   element j of lane l = W[k = ks*32 + (l>>4)*8 + j][col = n*16 + (l&15)]
// col order: [0,128) mu | [128,640) u | [640,768) d
// ---------------------------------------------------------------------------
__global__ void prep_kernel(const float* __restrict__ Wmu, const float* __restrict__ bmu,
                            const float* __restrict__ Wu,  const float* __restrict__ bu,
                            const float* __restrict__ Wd,  const float* __restrict__ bd,
                            short* __restrict__ Bfrag, float* __restrict__ bias,
                            float* __restrict__ out) {
    int t = blockIdx.x * blockDim.x + threadIdx.x;
    const int NFRAG = 48 * 16 * 64;
    if (t < NFRAG) {
        int l  = t & 63;
        int ks = (t >> 6) & 15;
        int n  = t >> 10;
        int col = n * 16 + (l & 15);
        int k0  = ks * 32 + (l >> 4) * 8;
        const float* src; int sc, ld;
        if (col < LAT)          { src = Wmu; sc = col;           ld = LAT;     }
        else if (col < LAT * 5) { src = Wu;  sc = col - LAT;     ld = LAT * 4; }
        else                    { src = Wd;  sc = col - LAT * 5; ld = LAT;     }
        bf16x8 v;
        #pragma unroll
        for (int j = 0; j < 8; ++j) v[j] = f2bf(src[(size_t)(k0 + j) * ld + sc]);
        ((bf16x8*)Bfrag)[t] = v;
    } else if (t < NFRAG + NCOL) {
        int col = t - NFRAG;
        float b;
        if (col < LAT)          b = bmu[col];
        else if (col < LAT * 5) b = bu[col - LAT];
        else                    b = bd[col - LAT * 5];
        bias[col] = b;
    } else if (t == NFRAG + NCOL) {
        *out = 0.0f;
    }
}

// ---------------------------------------------------------------------------
// fused: 64-row block, all 768 cols, K=512. 8 waves, wave w -> cols [96w,96w+96).
// A (x rows) staged bf16 in LDS, double-buffered 64-k chunks, frag-ready layout.
// Epilogue: fp32 dump to LDS (2 passes of 32 rows), per-row KL, atomicAdd.
// ---------------------------------------------------------------------------
__launch_bounds__(512, 2)
__global__ void fused_kernel(const float* __restrict__ x, const short* __restrict__ Bfrag,
                             const float* __restrict__ bias, float* __restrict__ out) {
    __shared__ __align__(16) short Abuf[2][4096];   // 2 x 8 KB: 64 rows x 64 k bf16
    __shared__ __align__(16) float Epi[32 * 772];   // 32 rows x (768 + 4 pad)
    __shared__ float bsum;

    const int tid  = threadIdx.x;
    const int l    = tid & 63;
    const int w    = tid >> 6;
    const int row0 = blockIdx.x * BM;

    // staging role: wave w stages row-tile (w&3), k-half (w>>2) of each 64-k chunk
    const int srt  = w & 3;
    const int sks  = w >> 2;
    const int srow = srt * 16 + (l & 15);
    const int skk  = sks * 32 + (l >> 4) * 8;
    const int awr  = ((sks * 4 + srt) * 64 + l) * 8;    // shorts

    const float*  xrow = x + (size_t)(row0 + srow) * HID + skk;
    const bf16x8* bwp  = (const bf16x8*)Bfrag + (size_t)w * 6 * 16 * 64 + l;

    f32x4 acc[4][6];
    #pragma unroll
    for (int rt = 0; rt < 4; ++rt)
        #pragma unroll
        for (int i = 0; i < 6; ++i) acc[rt][i] = (f32x4){0.f, 0.f, 0.f, 0.f};

    // B ping-pong register buffers (no copies of in-flight loads)
    bf16x8 b0[6], b1[6];
    #pragma unroll
    for (int i = 0; i < 6; ++i) b0[i] = bwp[(size_t)i * 16 * 64];   // ks = 0

    // stage chunk 0 into buf 0
    {
        f32x4 q0 = *(const f32x4*)(xrow);
        f32x4 q1 = *(const f32x4*)(xrow + 4);
        bf16x8 av;
        av[0]=f2bf(q0[0]); av[1]=f2bf(q0[1]); av[2]=f2bf(q0[2]); av[3]=f2bf(q0[3]);
        av[4]=f2bf(q1[0]); av[5]=f2bf(q1[1]); av[6]=f2bf(q1[2]); av[7]=f2bf(q1[3]);
        *(bf16x8*)&Abuf[0][awr] = av;
    }
    if (tid == 0) bsum = 0.0f;
    __syncthreads();

    f32x4 p0, p1;
    #pragma unroll
    for (int c = 0; c < 8; ++c) {
        const int buf = c & 1;
        // ---- k-step 2c (uses b0) ----
        #pragma unroll
        for (int i = 0; i < 6; ++i) b1[i] = bwp[((size_t)i * 16 + (2 * c + 1)) * 64];
        if (c < 7) {                         // issue next x chunk loads early
            const float* xq = xrow + (c + 1) * 64;
            p0 = *(const f32x4*)(xq);
            p1 = *(const f32x4*)(xq + 4);
        }
        #pragma unroll
        for (int rt = 0; rt < 4; ++rt) {
            bf16x8 av = *(const bf16x8*)&Abuf[buf][(rt * 64 + l) * 8];
            #pragma unroll
            for (int i = 0; i < 6; ++i)
                acc[rt][i] = __builtin_amdgcn_mfma_f32_16x16x32_bf16(av, b0[i], acc[rt][i], 0, 0, 0);
        }
        // ---- k-step 2c+1 (uses b1) ----
        if (c < 7) {
            #pragma unroll
            for (int i = 0; i < 6; ++i) b0[i] = bwp[((size_t)i * 16 + (2 * c + 2)) * 64];
        }
        #pragma unroll
        for (int rt = 0; rt < 4; ++rt) {
            bf16x8 av = *(const bf16x8*)&Abuf[buf][((4 + rt) * 64 + l) * 8];
            #pragma unroll
            for (int i = 0; i < 6; ++i)
                acc[rt][i] = __builtin_amdgcn_mfma_f32_16x16x32_bf16(av, b1[i], acc[rt][i], 0, 0, 0);
        }
        if (c < 7) {                         // write-late: convert + LDS write, then barrier
            bf16x8 av;
            av[0]=f2bf(p0[0]); av[1]=f2bf(p0[1]); av[2]=f2bf(p0[2]); av[3]=f2bf(p0[3]);
            av[4]=f2bf(p1[0]); av[5]=f2bf(p1[1]); av[6]=f2bf(p1[2]); av[7]=f2bf(p1[3]);
            *(bf16x8*)&Abuf[buf ^ 1][awr] = av;
            __syncthreads();
        }
    }

    // ------------------------- epilogue -------------------------
    float pre_bias[6];
    #pragma unroll
    for (int i = 0; i < 6; ++i) pre_bias[i] = bias[(w * 6 + i) * 16 + (l & 15)];

    float my_kl = 0.0f;
    const int r16 = tid >> 4;    // local row 0..31
    const int jj  = tid & 15;    // latent-stride lane

    #pragma unroll
    for (int pass = 0; pass < 2; ++pass) {
        // dump 32 rows (frags rt = 2*pass, 2*pass+1), fp32 + bias
        #pragma unroll
        for (int rt2 = 0; rt2 < 2; ++rt2) {
            const int rt    = pass * 2 + rt2;
            const int rbase = rt2 * 16 + (l >> 4) * 4;
            #pragma unroll
            for (int i = 0; i < 6; ++i) {
                const int col = (w * 6 + i) * 16 + (l & 15);
                #pragma unroll
                for (int j = 0; j < 4; ++j)
                    Epi[(rbase + j) * 772 + col] = acc[rt][i][j] + pre_bias[i];
            }
        }
        __syncthreads();

        const float* rowp = &Epi[r16 * 772];
        float s_mu2=0.f, s_u2=0.f, s_d=0.f, s_td=0.f;
        float m00=0.f,m01=0.f,m02=0.f,m03=0.f,m11=0.f,m12=0.f,m13=0.f,m22=0.f,m23=0.f,m33=0.f;
        #pragma unroll
        for (int t8 = 0; t8 < 8; ++t8) {
            const int a = jj + 16 * t8;                   // latent index, stride 16 (bank-free)
            float mu = rowp[a];
            float td = rowp[640 + a];
            f32x4 u4 = *(const f32x4*)&rowp[128 + 4 * a];
            s_mu2 += mu * mu;
            s_td  += td;
            float ed  = __expf(td);
            float eid = __expf(-td);
            s_d  += ed;
            s_u2 += u4[0]*u4[0] + u4[1]*u4[1] + u4[2]*u4[2] + u4[3]*u4[3];
            m00 += u4[0]*u4[0]*eid; m01 += u4[0]*u4[1]*eid;
            m02 += u4[0]*u4[2]*eid; m03 += u4[0]*u4[3]*eid;
            m11 += u4[1]*u4[1]*eid; m12 += u4[1]*u4[2]*eid;
            m13 += u4[1]*u4[3]*eid; m22 += u4[2]*u4[2]*eid;
            m23 += u4[2]*u4[3]*eid; m33 += u4[3]*u4[3]*eid;
        }
        #define XRED(v) { v += __shfl_xor(v,1); v += __shfl_xor(v,2); v += __shfl_xor(v,4); v += __shfl_xor(v,8); }
        XRED(s_mu2) XRED(s_u2) XRED(s_d) XRED(s_td)
        XRED(m00) XRED(m01) XRED(m02) XRED(m03) XRED(m11)
        XRED(m12) XRED(m13) XRED(m22) XRED(m23) XRED(m33)

        if (jj == 0) {
            // logdet(I + MtM) by symmetric Gaussian elimination; pivots >= 1
            float a00=1.f+m00, a01=m01, a02=m02, a03=m03;
            float a11=1.f+m11, a12=m12, a13=m13;
            float a22=1.f+m22, a23=m23, a33=1.f+m33;
            float i00 = 1.f / a00;
            float t01=a01*i00, t02=a02*i00, t03=a03*i00;
            a11 -= t01*a01; a12 -= t01*a02; a13 -= t01*a03;
            a22 -= t02*a02; a23 -= t02*a03;
            a33 -= t03*a03;
            float i11 = 1.f / a11;
            float t12=a12*i11, t13=a13*i11;
            a22 -= t12*a12; a23 -= t12*a13;
            a33 -= t13*a13;
            float t23 = a23 / a22;
            a33 -= t23*a23;
            float logdet = __logf(a00 * a11 * a22 * a33);
            // kl*2 (scale by 0.5 at the end):
            my_kl += s_d + s_u2 + s_mu2 - (float)LAT - s_td - logdet;
        }
        __syncthreads();
    }

    // block reduction: jj==0 lanes are l = 0,16,32,48 in each wave
    my_kl += __shfl_xor(my_kl, 16);
    my_kl += __shfl_xor(my_kl, 32);
    if (l == 0) atomicAdd(&bsum, my_kl);
    __syncthreads();
    if (tid == 0) atomicAdd(out, bsum * (0.5f / (float)NROWS));
}

extern "C" void kernel_launch(void* const* d_in, const int* in_sizes, int n_in,
                              void* d_out, int out_size, void* d_ws, size_t ws_size,
                              hipStream_t stream) {
    (void)in_sizes; (void)n_in; (void)out_size;
    const float* x   = (const float*)d_in[0];
    const float* Wmu = (const float*)d_in[1];
    const float* bmu = (const float*)d_in[2];
    const float* Wu  = (const float*)d_in[3];
    const float* bu  = (const float*)d_in[4];
    const float* Wd  = (const float*)d_in[5];
    const float* bd  = (const float*)d_in[6];
    if (ws_size < (size_t)(48 * 16 * 64 * 16 + NCOL * 4)) return;  // never expected

    short* Bfrag = (short*)d_ws;
    float* bias  = (float*)((char*)d_ws + 48 * 16 * 64 * 16);
    float* out   = (float*)d_out;

    prep_kernel<<<196, 256, 0, stream>>>(Wmu, bmu, Wu, bu, Wd, bd, Bfrag, bias, out);
    fused_kernel<<<NROWS / BM, 512, 0, stream>>>(x, Bfrag, bias, out);
}